// Round 3
// baseline (9458.841 us; speedup 1.0000x reference)
//
#include <hip/hip_runtime.h>
#include <math.h>

#define T_LEN 76800
#define T_MEL 300
#define B_N 4

typedef __attribute__((ext_vector_type(8))) short bf16x8;
typedef __attribute__((ext_vector_type(4))) float f32x4;

__device__ inline unsigned short f2bf(float x) {
    unsigned u = __float_as_uint(x);
    u += 0x7fffu + ((u >> 16) & 1u);
    return (unsigned short)(u >> 16);
}
__device__ inline float bf2f(unsigned short h) {
    return __uint_as_float(((unsigned)h) << 16);
}

// ---------------- prep kernels ----------------

__global__ void cu0_kernel(const float* __restrict__ c, const float* __restrict__ up_in_w,
                           float* __restrict__ cu0) {
    int idx = blockIdx.x * 256 + threadIdx.x;
    if (idx >= B_N * 80 * T_MEL) return;
    int m = idx % T_MEL; int rest = idx / T_MEL; int o = rest % 80; int b = rest / 80;
    const float* crow = c + (size_t)(b * 80) * T_MEL;
    const float* wrow = up_in_w + o * 80;
    float acc = 0.f;
    for (int i = 0; i < 80; ++i) acc = fmaf(wrow[i], crow[(size_t)i * T_MEL + m], acc);
    cu0[idx] = acc;
}

// composite 33-tap filter prefix sums + exact edge vectors (see r1 derivation)
__global__ void filt_kernel(const float* __restrict__ up_conv_w, float* __restrict__ filt) {
    if (threadIdx.x != 0 || blockIdx.x != 0) return;
    float F[33], tmp[33];
    for (int j = 0; j < 9; ++j) F[j] = up_conv_w[j];
    int len = 9;
    for (int s = 1; s < 4; ++s) {
        const float* w = up_conv_w + s * 9;
        int nl = len + 8;
        for (int j = 0; j < nl; ++j) {
            float acc = 0.f;
            for (int a = 0; a < 9; ++a) { int bi = j - a; if (bi >= 0 && bi < len) acc += w[a] * F[bi]; }
            tmp[j] = acc;
        }
        for (int j = 0; j < nl; ++j) F[j] = tmp[j];
        len = nl;
    }
    float run = 0.f;
    for (int n = 0; n < 33; ++n) { filt[n] = run; run += F[n]; }
    filt[33] = run; filt[34] = run;
    const float* w1 = up_conv_w + 0;  const float* w2 = up_conv_w + 9;
    const float* w3 = up_conv_w + 18; const float* w4 = up_conv_w + 27;
    {
        float y1[28], y2[24], y3[20];
        for (int u = 0; u < 28; ++u) { float a = 0; for (int k = 0; k < 9; ++k) { int v = u + k - 4; if (v >= 0) a += w1[k]; } y1[u] = a; }
        for (int u = 0; u < 24; ++u) { float a = 0; for (int k = 0; k < 9; ++k) { int v = u + k - 4; if (v >= 0) a += w2[k] * y1[v]; } y2[u] = a; }
        for (int u = 0; u < 20; ++u) { float a = 0; for (int k = 0; k < 9; ++k) { int v = u + k - 4; if (v >= 0) a += w3[k] * y2[v]; } y3[u] = a; }
        for (int t = 0; t < 16; ++t) { float a = 0; for (int k = 0; k < 9; ++k) { int v = t + k - 4; if (v >= 0) a += w4[k] * y3[v]; } filt[40 + t] = a; }
    }
    {
        float z1[44], z2[44], z3[44];
        for (int u = 0; u < 44; ++u) { float a = 0; for (int k = 0; k < 9; ++k) { int v = u + k - 4; if (v <= 43) a += w1[k]; } z1[u] = a; }
        for (int u = 0; u < 44; ++u) { float a = 0; for (int k = 0; k < 9; ++k) { int v = u + k - 4; if (v <= 43) a += w2[k] * z1[v < 0 ? 0 : v]; } z2[u] = a; }
        for (int u = 0; u < 44; ++u) { float a = 0; for (int k = 0; k < 9; ++k) { int v = u + k - 4; if (v <= 43) a += w3[k] * z2[v < 0 ? 0 : v]; } z3[u] = a; }
        for (int j = 0; j < 16; ++j) {
            int u = 28 + j; float a = 0;
            for (int k = 0; k < 9; ++k) { int v = u + k - 4; if (v <= 43) a += w4[k] * z3[v < 0 ? 0 : v]; }
            filt[56 + j] = a;
        }
    }
}

__global__ void g_kernel(const float* __restrict__ cu0, const float* __restrict__ aux_w,
                         float* __restrict__ g) {
    int idx = blockIdx.x * 256 + threadIdx.x;
    if (idx >= 30 * B_N * 128 * T_MEL) return;
    int m = idx % T_MEL; int rest = idx / T_MEL; int o = rest % 128; rest /= 128;
    int b = rest % B_N; int i = rest / B_N;
    const float* wrow = aux_w + ((size_t)i * 128 + o) * 80;
    const float* crow = cu0 + (size_t)(b * 80) * T_MEL + m;
    float acc = 0.f;
    for (int cc = 0; cc < 80; ++cc) acc = fmaf(wrow[cc], crow[(size_t)cc * T_MEL], acc);
    g[idx] = acc;
}

__global__ void first_kernel(const float* __restrict__ noise, const float* __restrict__ fw,
                             const float* __restrict__ fb, float* __restrict__ x) {
    int idx = blockIdx.x * 256 + threadIdx.x;
    if (idx >= B_N * 64 * T_LEN) return;
    int t = idx % T_LEN; int rest = idx / T_LEN; int o = rest % 64; int b = rest / 64;
    x[idx] = fmaf(fw[o], noise[(size_t)b * T_LEN + t], fb[o]);
}

// ---------------- main residual block: split-bf16 MFMA ----------------
// WG = 256 thr = 4 waves, tile 128 rows x 128 t. Wave w: all 8 M-tiles x 2 N-tiles
// (t in [w*32, w*32+32)). mfma_f32_16x16x32_bf16; split hi/lo: hh + hl + lh.
// Phase1: H = Wc[128][192] * X[192][t]; gate pairs (m, m+4) in-lane -> z.
// Phase2: [skip;out] = W2[128][64] * Z, z through LDS in two 32-kz halves.
__global__ __launch_bounds__(256) void block_kernel(
    const float* __restrict__ x_in, float* __restrict__ x_out,
    float* __restrict__ skip, const float* __restrict__ g,
    const float* __restrict__ filt,
    const float* __restrict__ conv_w, const float* __restrict__ conv_b,
    const float* __restrict__ skip_w, const float* __restrict__ skip_b,
    const float* __restrict__ out_w, const float* __restrict__ out_b,
    int d, int first) {
    // rows padded to 40 elems (80B): 16B-aligned b128, conflict-free-ish banks
    __shared__ unsigned short Whi[128 * 40], Wlo[128 * 40];
    __shared__ unsigned short Xhi[128 * 40], Xlo[128 * 40];
    __shared__ unsigned short Zhi[128 * 40], Zlo[128 * 40];
    __shared__ float glm[128], gll[128], glr[128], bl1[128], bl2[128];

    const int tid = threadIdx.x;
    const int wv = tid >> 6, ln = tid & 63;
    const int g4 = ln >> 4, l15 = ln & 15;
    const int b = blockIdx.y;
    const int t0 = blockIdx.x * 128;
    const int m0 = t0 >> 8;

    // ---- stage g columns + biases ----
    if (tid < 128) {
        int o = tid;
        const float* gb = g + ((size_t)b * 128 + o) * T_MEL;
        int ml = m0 > 0 ? m0 - 1 : 0;
        int mr = m0 < 299 ? m0 + 1 : 299;
        glm[o] = gb[m0]; gll[o] = gb[ml]; glr[o] = gb[mr];
        bl1[o] = conv_b[o];
    } else {
        int o = tid - 128;
        bl2[o] = (o < 64) ? skip_b[o] : out_b[o - 64];
    }
    __syncthreads();

    // ---- per-(ntile) aux interpolation coefficients (exact) ----
    float am[2], al[2], ar[2];
    const float K = filt[34];
    #pragma unroll
    for (int nt = 0; nt < 2; ++nt) {
        int t = t0 + wv * 32 + nt * 16 + l15;
        int r = t & 255;
        float Am = K, Al = 0.f, Ar = 0.f;
        if (t < 16)               { Am = filt[40 + t]; }
        else if (t >= T_LEN - 16) { Am = filt[56 + (t - (T_LEN - 16))]; }
        else if (r < 16)  { float blv = filt[16 - r];     Am = K - blv; Al = blv; }
        else if (r > 239) { float bh = K - filt[272 - r]; Am = K - bh;  Ar = bh; }
        am[nt] = Am; al[nt] = Al; ar[nt] = Ar;
    }

    // ---- acc init: bias + aux (fp32 exact) ----
    f32x4 acc[8][2];
    #pragma unroll
    for (int m = 0; m < 8; ++m)
        #pragma unroll
        for (int nt = 0; nt < 2; ++nt)
            #pragma unroll
            for (int r = 0; r < 4; ++r) {
                int o = m * 16 + 4 * g4 + r;
                acc[m][nt][r] = bl1[o] + am[nt] * glm[o] + al[nt] * gll[o] + ar[nt] * glr[o];
            }

    const float* xb = x_in + (size_t)b * 64 * T_LEN;

    // ---- phase 1: K=192 in 6 chunks of 32 ----
    #pragma unroll
    for (int ch = 0; ch < 6; ++ch) {
        const int k0 = ch * 32;
        {   // stage W chunk: thread o=tid>>1, 16 k
            int o = tid >> 1, kh = (tid & 1) << 4;
            const float* wr = conv_w + (size_t)o * 192 + k0 + kh;
            bf16x8 h0, h1, l0, l1;
            #pragma unroll
            for (int j = 0; j < 8; ++j) {
                float v = wr[j];
                unsigned short hb = f2bf(v); float hf = bf2f(hb);
                h0[j] = (short)hb; l0[j] = (short)f2bf(v - hf);
            }
            #pragma unroll
            for (int j = 0; j < 8; ++j) {
                float v = wr[8 + j];
                unsigned short hb = f2bf(v); float hf = bf2f(hb);
                h1[j] = (short)hb; l1[j] = (short)f2bf(v - hf);
            }
            *(bf16x8*)&Whi[o * 40 + kh]     = h0; *(bf16x8*)&Whi[o * 40 + kh + 8] = h1;
            *(bf16x8*)&Wlo[o * 40 + kh]     = l0; *(bf16x8*)&Wlo[o * 40 + kh + 8] = l1;
        }
        // stage X chunk transposed: [t][k] via global gather (coalesced in t)
        #pragma unroll
        for (int rep = 0; rep < 2; ++rep) {
            int tt = tid & 127;
            int kg = (rep << 1) | (tid >> 7);
            int tglob = t0 + tt;
            bf16x8 hv, lv;
            #pragma unroll
            for (int j = 0; j < 8; ++j) {
                int kk = k0 + kg * 8 + j;
                int i = kk / 3, tap = kk - 3 * i;
                int ts = tglob + (tap - 1) * d;
                float v = (ts >= 0 && ts < T_LEN) ? xb[(size_t)i * T_LEN + ts] : 0.f;
                unsigned short hb = f2bf(v); float hf = bf2f(hb);
                hv[j] = (short)hb; lv[j] = (short)f2bf(v - hf);
            }
            *(bf16x8*)&Xhi[tt * 40 + kg * 8] = hv;
            *(bf16x8*)&Xlo[tt * 40 + kg * 8] = lv;
        }
        __syncthreads();
        bf16x8 bxh[2], bxl[2];
        #pragma unroll
        for (int nt = 0; nt < 2; ++nt) {
            int tt = wv * 32 + nt * 16 + l15;
            bxh[nt] = *(const bf16x8*)&Xhi[tt * 40 + g4 * 8];
            bxl[nt] = *(const bf16x8*)&Xlo[tt * 40 + g4 * 8];
        }
        #pragma unroll
        for (int m = 0; m < 8; ++m) {
            int orow = m * 16 + l15;
            bf16x8 ah = *(const bf16x8*)&Whi[orow * 40 + g4 * 8];
            bf16x8 alo = *(const bf16x8*)&Wlo[orow * 40 + g4 * 8];
            #pragma unroll
            for (int nt = 0; nt < 2; ++nt) {
                acc[m][nt] = __builtin_amdgcn_mfma_f32_16x16x32_bf16(ah,  bxh[nt], acc[m][nt], 0, 0, 0);
                acc[m][nt] = __builtin_amdgcn_mfma_f32_16x16x32_bf16(ah,  bxl[nt], acc[m][nt], 0, 0, 0);
                acc[m][nt] = __builtin_amdgcn_mfma_f32_16x16x32_bf16(alo, bxh[nt], acc[m][nt], 0, 0, 0);
            }
        }
        __syncthreads();
    }

    // ---- stage W2: kstep0 -> W region, kstep1 -> X region ----
    {
        int o = tid >> 1, kh = (tid & 1) << 4;
        const float* wr = (o < 64) ? (skip_w + (size_t)o * 64) : (out_w + (size_t)(o - 64) * 64);
        bf16x8 h0, l0, h1, l1;
        #pragma unroll
        for (int j = 0; j < 8; ++j) {
            float v = wr[kh + j];
            unsigned short hb = f2bf(v); float hf = bf2f(hb);
            h0[j] = (short)hb; l0[j] = (short)f2bf(v - hf);
        }
        #pragma unroll
        for (int j = 0; j < 8; ++j) {
            float v = wr[kh + 8 + j];
            unsigned short hb = f2bf(v); float hf = bf2f(hb);
            h1[j] = (short)hb; l1[j] = (short)f2bf(v - hf);
        }
        *(bf16x8*)&Whi[o * 40 + kh] = h0; *(bf16x8*)&Whi[o * 40 + kh + 8] = h1;
        *(bf16x8*)&Wlo[o * 40 + kh] = l0; *(bf16x8*)&Wlo[o * 40 + kh + 8] = l1;
        bf16x8 h2, l2, h3, l3;
        #pragma unroll
        for (int j = 0; j < 8; ++j) {
            float v = wr[32 + kh + j];
            unsigned short hb = f2bf(v); float hf = bf2f(hb);
            h2[j] = (short)hb; l2[j] = (short)f2bf(v - hf);
        }
        #pragma unroll
        for (int j = 0; j < 8; ++j) {
            float v = wr[32 + kh + 8 + j];
            unsigned short hb = f2bf(v); float hf = bf2f(hb);
            h3[j] = (short)hb; l3[j] = (short)f2bf(v - hf);
        }
        *(bf16x8*)&Xhi[o * 40 + kh] = h2; *(bf16x8*)&Xhi[o * 40 + kh + 8] = h3;
        *(bf16x8*)&Xlo[o * 40 + kh] = l2; *(bf16x8*)&Xlo[o * 40 + kh + 8] = l3;
    }

    f32x4 acc2[8][2];
    #pragma unroll
    for (int m = 0; m < 8; ++m)
        #pragma unroll
        for (int nt = 0; nt < 2; ++nt)
            #pragma unroll
            for (int r = 0; r < 4; ++r)
                acc2[m][nt][r] = bl2[m * 16 + 4 * g4 + r];

    // ---- phase 2 in two kz-halves ----
    #pragma unroll
    for (int hp = 0; hp < 2; ++hp) {
        if (hp) __syncthreads();  // prior half's reads must finish before Z overwrite
        #pragma unroll
        for (int zm2 = 0; zm2 < 2; ++zm2) {
            int zm = hp * 2 + zm2;
            #pragma unroll
            for (int nt = 0; nt < 2; ++nt) {
                int tt = wv * 32 + nt * 16 + l15;
                unsigned ph[2], pl[2];
                #pragma unroll
                for (int r2 = 0; r2 < 2; ++r2) {
                    unsigned short zh_[2], zl_[2];
                    #pragma unroll
                    for (int q = 0; q < 2; ++q) {
                        int r = r2 * 2 + q;
                        float a_ = acc[zm][nt][r], b_ = acc[zm + 4][nt][r];
                        float z = tanhf(a_) * (1.f / (1.f + expf(-b_)));
                        unsigned short hb = f2bf(z); float hf = bf2f(hb);
                        zh_[q] = hb; zl_[q] = f2bf(z - hf);
                    }
                    ph[r2] = (unsigned)zh_[0] | ((unsigned)zh_[1] << 16);
                    pl[r2] = (unsigned)zl_[0] | ((unsigned)zl_[1] << 16);
                }
                int ei = tt * 40 + zm2 * 16 + 4 * g4;
                uint2 vh; vh.x = ph[0]; vh.y = ph[1];
                uint2 vl; vl.x = pl[0]; vl.y = pl[1];
                *(uint2*)&Zhi[ei] = vh;
                *(uint2*)&Zlo[ei] = vl;
            }
        }
        __syncthreads();
        const unsigned short* W2h = hp ? Xhi : Whi;
        const unsigned short* W2l = hp ? Xlo : Wlo;
        bf16x8 bzh[2], bzl[2];
        #pragma unroll
        for (int nt = 0; nt < 2; ++nt) {
            int tt = wv * 32 + nt * 16 + l15;
            bzh[nt] = *(const bf16x8*)&Zhi[tt * 40 + g4 * 8];
            bzl[nt] = *(const bf16x8*)&Zlo[tt * 40 + g4 * 8];
        }
        #pragma unroll
        for (int m = 0; m < 8; ++m) {
            int orow = m * 16 + l15;
            bf16x8 ah = *(const bf16x8*)&W2h[orow * 40 + g4 * 8];
            bf16x8 alo = *(const bf16x8*)&W2l[orow * 40 + g4 * 8];
            #pragma unroll
            for (int nt = 0; nt < 2; ++nt) {
                acc2[m][nt] = __builtin_amdgcn_mfma_f32_16x16x32_bf16(ah,  bzh[nt], acc2[m][nt], 0, 0, 0);
                acc2[m][nt] = __builtin_amdgcn_mfma_f32_16x16x32_bf16(ah,  bzl[nt], acc2[m][nt], 0, 0, 0);
                acc2[m][nt] = __builtin_amdgcn_mfma_f32_16x16x32_bf16(alo, bzh[nt], acc2[m][nt], 0, 0, 0);
            }
        }
    }

    // ---- epilogue: rows 0-63 skip accumulate, 64-127 residual out ----
    #pragma unroll
    for (int m = 0; m < 8; ++m)
        #pragma unroll
        for (int nt = 0; nt < 2; ++nt) {
            int t = t0 + wv * 32 + nt * 16 + l15;
            #pragma unroll
            for (int r = 0; r < 4; ++r) {
                int o2 = m * 16 + 4 * g4 + r;
                float v = acc2[m][nt][r];
                if (m < 4) {
                    size_t off = ((size_t)b * 64 + o2) * T_LEN + t;
                    skip[off] = first ? v : (skip[off] + v);
                } else {
                    size_t off = ((size_t)b * 64 + (o2 - 64)) * T_LEN + t;
                    x_out[off] = (v + x_in[off]) * 0.25f;
                }
            }
        }
}

// ---------------- epilogue ----------------
__global__ void final_kernel(const float* __restrict__ skip,
                             const float* __restrict__ l1w, const float* __restrict__ l1b,
                             const float* __restrict__ l2w, const float* __restrict__ l2b,
                             float* __restrict__ out) {
    int idx = blockIdx.x * 256 + threadIdx.x;
    if (idx >= B_N * T_LEN) return;
    int t = idx % T_LEN; int b = idx / T_LEN;
    const float scale = 0.18257418583505536f; // sqrt(1/30)
    float rbuf[64];
    const float* srow = skip + (size_t)b * 64 * T_LEN + t;
    #pragma unroll
    for (int s = 0; s < 64; ++s) {
        float v = srow[(size_t)s * T_LEN] * scale;
        rbuf[s] = v > 0.f ? v : 0.f;
    }
    float oacc = l2b[0];
    for (int cch = 0; cch < 64; ++cch) {
        float a = l1b[cch];
        const float* wrow = l1w + (size_t)cch * 64;
        #pragma unroll
        for (int s = 0; s < 64; ++s) a = fmaf(wrow[s], rbuf[s], a);
        a = a > 0.f ? a : 0.f;
        oacc = fmaf(l2w[cch], a, oacc);
    }
    out[idx] = oacc;
}

// ---------------- launch ----------------
extern "C" void kernel_launch(void* const* d_in, const int* in_sizes, int n_in,
                              void* d_out, int out_size, void* d_ws, size_t ws_size,
                              hipStream_t stream) {
    const float* c          = (const float*)d_in[0];
    const float* noise      = (const float*)d_in[1];
    const float* first_w    = (const float*)d_in[2];
    const float* first_b    = (const float*)d_in[3];
    const float* up_in_w    = (const float*)d_in[4];
    const float* up_conv_w  = (const float*)d_in[5];
    const float* blk_conv_w = (const float*)d_in[6];
    const float* blk_conv_b = (const float*)d_in[7];
    const float* blk_aux_w  = (const float*)d_in[8];
    const float* blk_out_w  = (const float*)d_in[9];
    const float* blk_out_b  = (const float*)d_in[10];
    const float* blk_skip_w = (const float*)d_in[11];
    const float* blk_skip_b = (const float*)d_in[12];
    const float* last1_w    = (const float*)d_in[13];
    const float* last1_b    = (const float*)d_in[14];
    const float* last2_w    = (const float*)d_in[15];
    const float* last2_b    = (const float*)d_in[16];
    float* out = (float*)d_out;
    float* ws  = (float*)d_ws;

    size_t off = 0;
    float* cu0  = ws + off; off += 96256;
    float* g    = ws + off; off += 30ull * 4 * 128 * T_MEL;
    float* filt = ws + off; off += 128;
    float* xA   = ws + off; off += 4ull * 64 * T_LEN;
    float* xB   = ws + off; off += 4ull * 64 * T_LEN;
    float* skip = ws + off; off += 4ull * 64 * T_LEN;
    if (ws_size < off * sizeof(float)) return;

    hipLaunchKernelGGL(cu0_kernel, dim3((B_N * 80 * T_MEL + 255) / 256), dim3(256), 0, stream,
                       c, up_in_w, cu0);
    hipLaunchKernelGGL(filt_kernel, dim3(1), dim3(64), 0, stream, up_conv_w, filt);
    hipLaunchKernelGGL(g_kernel, dim3((30 * B_N * 128 * T_MEL + 255) / 256), dim3(256), 0, stream,
                       cu0, blk_aux_w, g);
    hipLaunchKernelGGL(first_kernel, dim3((B_N * 64 * T_LEN + 255) / 256), dim3(256), 0, stream,
                       noise, first_w, first_b, xA);

    for (int i = 0; i < 30; ++i) {
        int dd = 1 << (i % 10);
        const float* xin = (i & 1) ? xB : xA;
        float* xout      = (i & 1) ? xA : xB;
        hipLaunchKernelGGL(block_kernel, dim3(T_LEN / 128, B_N), dim3(256), 0, stream,
                           xin, xout, skip,
                           g + (size_t)i * 4 * 128 * T_MEL, filt,
                           blk_conv_w + (size_t)i * 128 * 64 * 3,
                           blk_conv_b + (size_t)i * 128,
                           blk_skip_w + (size_t)i * 64 * 64,
                           blk_skip_b + (size_t)i * 64,
                           blk_out_w + (size_t)i * 64 * 64,
                           blk_out_b + (size_t)i * 64,
                           dd, i == 0 ? 1 : 0);
    }

    hipLaunchKernelGGL(final_kernel, dim3((B_N * T_LEN + 255) / 256), dim3(256), 0, stream,
                       skip, last1_w, last1_b, last2_w, last2_b, out);
}

// Round 4
// 9099.755 us; speedup vs baseline: 1.0395x; 1.0395x over previous
//
#include <hip/hip_runtime.h>
#include <math.h>

#define T_LEN 76800
#define T_MEL 300
#define B_N 4

typedef __attribute__((ext_vector_type(8))) short bf16x8;
typedef __attribute__((ext_vector_type(4))) float f32x4;
typedef __attribute__((ext_vector_type(4))) unsigned short u16x4;

__device__ inline unsigned short f2bf(float x) {
    unsigned u = __float_as_uint(x);
    u += 0x7fffu + ((u >> 16) & 1u);
    return (unsigned short)(u >> 16);
}
__device__ inline float bf2f(unsigned short h) {
    return __uint_as_float(((unsigned)h) << 16);
}

// ---------------- prep kernels ----------------

__global__ void cu0_kernel(const float* __restrict__ c, const float* __restrict__ up_in_w,
                           float* __restrict__ cu0) {
    int idx = blockIdx.x * 256 + threadIdx.x;
    if (idx >= B_N * 80 * T_MEL) return;
    int m = idx % T_MEL; int rest = idx / T_MEL; int o = rest % 80; int b = rest / 80;
    const float* crow = c + (size_t)(b * 80) * T_MEL;
    const float* wrow = up_in_w + o * 80;
    float acc = 0.f;
    for (int i = 0; i < 80; ++i) acc = fmaf(wrow[i], crow[(size_t)i * T_MEL + m], acc);
    cu0[idx] = acc;
}

// composite 33-tap filter prefix sums + exact edge vectors (r1 derivation, validated)
__global__ void filt_kernel(const float* __restrict__ up_conv_w, float* __restrict__ filt) {
    if (threadIdx.x != 0 || blockIdx.x != 0) return;
    float F[33], tmp[33];
    for (int j = 0; j < 9; ++j) F[j] = up_conv_w[j];
    int len = 9;
    for (int s = 1; s < 4; ++s) {
        const float* w = up_conv_w + s * 9;
        int nl = len + 8;
        for (int j = 0; j < nl; ++j) {
            float acc = 0.f;
            for (int a = 0; a < 9; ++a) { int bi = j - a; if (bi >= 0 && bi < len) acc += w[a] * F[bi]; }
            tmp[j] = acc;
        }
        for (int j = 0; j < nl; ++j) F[j] = tmp[j];
        len = nl;
    }
    float run = 0.f;
    for (int n = 0; n < 33; ++n) { filt[n] = run; run += F[n]; }
    filt[33] = run; filt[34] = run;
    const float* w1 = up_conv_w + 0;  const float* w2 = up_conv_w + 9;
    const float* w3 = up_conv_w + 18; const float* w4 = up_conv_w + 27;
    {
        float y1[28], y2[24], y3[20];
        for (int u = 0; u < 28; ++u) { float a = 0; for (int k = 0; k < 9; ++k) { int v = u + k - 4; if (v >= 0) a += w1[k]; } y1[u] = a; }
        for (int u = 0; u < 24; ++u) { float a = 0; for (int k = 0; k < 9; ++k) { int v = u + k - 4; if (v >= 0) a += w2[k] * y1[v]; } y2[u] = a; }
        for (int u = 0; u < 20; ++u) { float a = 0; for (int k = 0; k < 9; ++k) { int v = u + k - 4; if (v >= 0) a += w3[k] * y2[v]; } y3[u] = a; }
        for (int t = 0; t < 16; ++t) { float a = 0; for (int k = 0; k < 9; ++k) { int v = t + k - 4; if (v >= 0) a += w4[k] * y3[v]; } filt[40 + t] = a; }
    }
    {
        float z1[44], z2[44], z3[44];
        for (int u = 0; u < 44; ++u) { float a = 0; for (int k = 0; k < 9; ++k) { int v = u + k - 4; if (v <= 43) a += w1[k]; } z1[u] = a; }
        for (int u = 0; u < 44; ++u) { float a = 0; for (int k = 0; k < 9; ++k) { int v = u + k - 4; if (v <= 43) a += w2[k] * z1[v < 0 ? 0 : v]; } z2[u] = a; }
        for (int u = 0; u < 44; ++u) { float a = 0; for (int k = 0; k < 9; ++k) { int v = u + k - 4; if (v <= 43) a += w3[k] * z2[v < 0 ? 0 : v]; } z3[u] = a; }
        for (int j = 0; j < 16; ++j) {
            int u = 28 + j; float a = 0;
            for (int k = 0; k < 9; ++k) { int v = u + k - 4; if (v <= 43) a += w4[k] * z3[v < 0 ? 0 : v]; }
            filt[56 + j] = a;
        }
    }
}

__global__ void g_kernel(const float* __restrict__ cu0, const float* __restrict__ aux_w,
                         float* __restrict__ g) {
    int idx = blockIdx.x * 256 + threadIdx.x;
    if (idx >= 30 * B_N * 128 * T_MEL) return;
    int m = idx % T_MEL; int rest = idx / T_MEL; int o = rest % 128; rest /= 128;
    int b = rest % B_N; int i = rest / B_N;
    const float* wrow = aux_w + ((size_t)i * 128 + o) * 80;
    const float* crow = cu0 + (size_t)(b * 80) * T_MEL + m;
    float acc = 0.f;
    for (int cc = 0; cc < 80; ++cc) acc = fmaf(wrow[cc], crow[(size_t)cc * T_MEL], acc);
    g[idx] = acc;
}

// x0 in [b][t][ch] split-bf16 layout
__global__ void first_kernel(const float* __restrict__ noise, const float* __restrict__ fw,
                             const float* __restrict__ fb,
                             unsigned short* __restrict__ xh, unsigned short* __restrict__ xl) {
    int idx = blockIdx.x * 256 + threadIdx.x;
    if (idx >= B_N * T_LEN * 64) return;
    int i = idx & 63; int rest = idx >> 6; int t = rest % T_LEN; int b = rest / T_LEN;
    float v = fmaf(fw[i], noise[(size_t)b * T_LEN + t], fb[i]);
    unsigned short h = f2bf(v);
    xh[idx] = h;
    xl[idx] = f2bf(v - bf2f(h));
}

// conv weights -> MFMA A-fragment order, hi/lo planes.
// idx = (((layer*3+tap)*2+ch)*8+m)*64+lane ; elem j: o=m*16+(l&15), i=ch*32+(l>>4)*8+j
__global__ void wfrag_kernel(const float* __restrict__ conv_w,
                             unsigned short* __restrict__ wfh, unsigned short* __restrict__ wfl) {
    int idx = blockIdx.x * 256 + threadIdx.x;
    if (idx >= 30 * 3 * 2 * 8 * 64) return;
    int l = idx & 63; int r = idx >> 6;
    int m = r & 7; r >>= 3;
    int ch = r & 1; r >>= 1;
    int tap = r % 3; int layer = r / 3;
    int o = m * 16 + (l & 15);
    int i0 = ch * 32 + (l >> 4) * 8;
    #pragma unroll
    for (int j = 0; j < 8; ++j) {
        float v = conv_w[(((size_t)layer * 128 + o) * 64 + i0 + j) * 3 + tap];
        unsigned short h = f2bf(v);
        wfh[(size_t)idx * 8 + j] = h;
        wfl[(size_t)idx * 8 + j] = f2bf(v - bf2f(h));
    }
}

// skip/out weights -> fragment order. idx = ((layer*2+ch)*8+m)*64+lane
__global__ void w2frag_kernel(const float* __restrict__ skip_w, const float* __restrict__ out_w,
                              unsigned short* __restrict__ w2h, unsigned short* __restrict__ w2l) {
    int idx = blockIdx.x * 256 + threadIdx.x;
    if (idx >= 30 * 2 * 8 * 64) return;
    int l = idx & 63; int r = idx >> 6;
    int m = r & 7; r >>= 3;
    int ch = r & 1; int layer = r >> 1;
    int o = m * 16 + (l & 15);
    int z0 = ch * 32 + (l >> 4) * 8;
    #pragma unroll
    for (int j = 0; j < 8; ++j) {
        float v = (o < 64) ? skip_w[((size_t)layer * 64 + o) * 64 + z0 + j]
                           : out_w[((size_t)layer * 64 + (o - 64)) * 64 + z0 + j];
        unsigned short h = f2bf(v);
        w2h[(size_t)idx * 8 + j] = h;
        w2l[(size_t)idx * 8 + j] = f2bf(v - bf2f(h));
    }
}

// ---------------- main residual block ----------------
// 256 thr = 4 waves; tile 128 o-rows x 128 t. Wave wv owns t in [wv*32, wv*32+32).
// Phase1: 3 tap-GEMMs K=64 (2 chunks of 32): A = pre-split W frags (global),
//         B = x [b][t][ch] split planes (direct global loads, uniform bounds check).
//         No LDS, no barriers, no conversions.
// Gate in-register (pairs m, m+4) -> z hi/lo -> LDS [t][zc] -> Phase2 GEMM K=64.
__global__ __launch_bounds__(256) void block_kernel(
    const unsigned short* __restrict__ xin_h, const unsigned short* __restrict__ xin_l,
    unsigned short* __restrict__ xout_h, unsigned short* __restrict__ xout_l,
    float* __restrict__ skip, const float* __restrict__ g, const float* __restrict__ filt,
    const unsigned short* __restrict__ wfh, const unsigned short* __restrict__ wfl,
    const float* __restrict__ conv_b,
    const unsigned short* __restrict__ w2h, const unsigned short* __restrict__ w2l,
    const float* __restrict__ skip_b, const float* __restrict__ out_b,
    int d, int first)
{
    __shared__ unsigned short Zh[128 * 72], Zl[128 * 72];
    __shared__ float glm[128], gll[128], glr[128], bl1[128], bl2[128];

    const int tid = threadIdx.x;
    const int wv = tid >> 6, ln = tid & 63;
    const int g4 = ln >> 4, l15 = ln & 15;
    const int b = blockIdx.y;
    const int t0 = blockIdx.x * 128;
    const int m0 = t0 >> 8;

    if (tid < 128) {
        int o = tid;
        const float* gb = g + ((size_t)b * 128 + o) * T_MEL;
        int ml = m0 > 0 ? m0 - 1 : 0;
        int mr = m0 < 299 ? m0 + 1 : 299;
        glm[o] = gb[m0]; gll[o] = gb[ml]; glr[o] = gb[mr];
        bl1[o] = conv_b[o];
    } else {
        int o = tid - 128;
        bl2[o] = (o < 64) ? skip_b[o] : out_b[o - 64];
    }
    __syncthreads();

    // per-ntile aux interpolation coefficients (exact)
    float am[2], al[2], ar[2];
    const float K = filt[34];
    #pragma unroll
    for (int nt = 0; nt < 2; ++nt) {
        int t = t0 + wv * 32 + nt * 16 + l15;
        int r = t & 255;
        float Am = K, Al = 0.f, Ar = 0.f;
        if (t < 16)               { Am = filt[40 + t]; }
        else if (t >= T_LEN - 16) { Am = filt[56 + (t - (T_LEN - 16))]; }
        else if (r < 16)  { float blv = filt[16 - r];     Am = K - blv; Al = blv; }
        else if (r > 239) { float bh = K - filt[272 - r]; Am = K - bh;  Ar = bh; }
        am[nt] = Am; al[nt] = Al; ar[nt] = Ar;
    }

    f32x4 acc[8][2];
    #pragma unroll
    for (int m = 0; m < 8; ++m)
        #pragma unroll
        for (int nt = 0; nt < 2; ++nt)
            #pragma unroll
            for (int r = 0; r < 4; ++r) {
                int o = m * 16 + 4 * g4 + r;
                acc[m][nt][r] = bl1[o] + am[nt] * glm[o] + al[nt] * gll[o] + ar[nt] * glr[o];
            }

    bf16x8 zfrag;
    #pragma unroll
    for (int j = 0; j < 8; ++j) zfrag[j] = 0;

    const size_t xbase = (size_t)b * T_LEN * 64;

    // ---- phase 1: 3 taps x 2 chunks, all operands straight from global ----
    #pragma unroll
    for (int tap = 0; tap < 3; ++tap) {
        const int shift = (tap - 1) * d;
        #pragma unroll
        for (int ch = 0; ch < 2; ++ch) {
            bf16x8 bxh[2], bxl[2];
            #pragma unroll
            for (int nt = 0; nt < 2; ++nt) {
                int te = t0 + wv * 32 + nt * 16 + l15 + shift;
                if ((unsigned)te < (unsigned)T_LEN) {
                    size_t a = xbase + (size_t)te * 64 + ch * 32 + g4 * 8;
                    bxh[nt] = *(const bf16x8*)(xin_h + a);
                    bxl[nt] = *(const bf16x8*)(xin_l + a);
                } else {
                    bxh[nt] = zfrag; bxl[nt] = zfrag;
                }
            }
            const int fb_ = ((tap * 2 + ch) * 8) * 64 * 8;
            #pragma unroll
            for (int m = 0; m < 8; ++m) {
                const bf16x8 ah = *(const bf16x8*)(wfh + fb_ + (m * 64 + ln) * 8);
                const bf16x8 alo = *(const bf16x8*)(wfl + fb_ + (m * 64 + ln) * 8);
                #pragma unroll
                for (int nt = 0; nt < 2; ++nt) {
                    acc[m][nt] = __builtin_amdgcn_mfma_f32_16x16x32_bf16(ah,  bxh[nt], acc[m][nt], 0, 0, 0);
                    acc[m][nt] = __builtin_amdgcn_mfma_f32_16x16x32_bf16(ah,  bxl[nt], acc[m][nt], 0, 0, 0);
                    acc[m][nt] = __builtin_amdgcn_mfma_f32_16x16x32_bf16(alo, bxh[nt], acc[m][nt], 0, 0, 0);
                }
            }
        }
    }

    // ---- gate -> z split -> LDS [t][zc] (zc contiguous) ----
    #pragma unroll
    for (int zm = 0; zm < 4; ++zm)
        #pragma unroll
        for (int nt = 0; nt < 2; ++nt) {
            u16x4 zh4, zl4;
            #pragma unroll
            for (int r = 0; r < 4; ++r) {
                float a_ = acc[zm][nt][r], b_ = acc[zm + 4][nt][r];
                float z = tanhf(a_) * (1.f / (1.f + expf(-b_)));
                unsigned short h = f2bf(z);
                zh4[r] = h; zl4[r] = f2bf(z - bf2f(h));
            }
            int twg = wv * 32 + nt * 16 + l15;
            int zc0 = zm * 16 + 4 * g4;
            *(u16x4*)&Zh[twg * 72 + zc0] = zh4;
            *(u16x4*)&Zl[twg * 72 + zc0] = zl4;
        }
    __syncthreads();

    // ---- phase 2: [skip;out] = W2 * Z ----
    f32x4 acc2[8][2];
    #pragma unroll
    for (int m = 0; m < 8; ++m)
        #pragma unroll
        for (int nt = 0; nt < 2; ++nt)
            #pragma unroll
            for (int r = 0; r < 4; ++r)
                acc2[m][nt][r] = bl2[m * 16 + 4 * g4 + r];

    #pragma unroll
    for (int ch = 0; ch < 2; ++ch) {
        bf16x8 bzh[2], bzl[2];
        #pragma unroll
        for (int nt = 0; nt < 2; ++nt) {
            int twg = wv * 32 + nt * 16 + l15;
            bzh[nt] = *(const bf16x8*)&Zh[twg * 72 + ch * 32 + g4 * 8];
            bzl[nt] = *(const bf16x8*)&Zl[twg * 72 + ch * 32 + g4 * 8];
        }
        #pragma unroll
        for (int m = 0; m < 8; ++m) {
            const bf16x8 ah = *(const bf16x8*)(w2h + ((ch * 8 + m) * 64 + ln) * 8);
            const bf16x8 alo = *(const bf16x8*)(w2l + ((ch * 8 + m) * 64 + ln) * 8);
            #pragma unroll
            for (int nt = 0; nt < 2; ++nt) {
                acc2[m][nt] = __builtin_amdgcn_mfma_f32_16x16x32_bf16(ah,  bzh[nt], acc2[m][nt], 0, 0, 0);
                acc2[m][nt] = __builtin_amdgcn_mfma_f32_16x16x32_bf16(ah,  bzl[nt], acc2[m][nt], 0, 0, 0);
                acc2[m][nt] = __builtin_amdgcn_mfma_f32_16x16x32_bf16(alo, bzh[nt], acc2[m][nt], 0, 0, 0);
            }
        }
    }

    // ---- epilogue ----
    #pragma unroll
    for (int m = 0; m < 4; ++m)
        #pragma unroll
        for (int nt = 0; nt < 2; ++nt) {
            int t = t0 + wv * 32 + nt * 16 + l15;
            #pragma unroll
            for (int r = 0; r < 4; ++r) {
                int o = m * 16 + 4 * g4 + r;
                size_t off = ((size_t)b * 64 + o) * T_LEN + t;
                float v = acc2[m][nt][r];
                skip[off] = first ? v : (skip[off] + v);
            }
        }
    #pragma unroll
    for (int m = 4; m < 8; ++m)
        #pragma unroll
        for (int nt = 0; nt < 2; ++nt) {
            int t = t0 + wv * 32 + nt * 16 + l15;
            int o0 = (m - 4) * 16 + 4 * g4;
            size_t a = xbase + (size_t)t * 64 + o0;
            u16x4 xh4 = *(const u16x4*)(xin_h + a);
            u16x4 xl4 = *(const u16x4*)(xin_l + a);
            u16x4 oh, ol;
            #pragma unroll
            for (int r = 0; r < 4; ++r) {
                float xi = bf2f(xh4[r]) + bf2f(xl4[r]);
                float v = (acc2[m][nt][r] + xi) * 0.25f;
                unsigned short h = f2bf(v);
                oh[r] = h; ol[r] = f2bf(v - bf2f(h));
            }
            *(u16x4*)(xout_h + a) = oh;
            *(u16x4*)(xout_l + a) = ol;
        }
}

// ---------------- epilogue ----------------
__global__ void final_kernel(const float* __restrict__ skip,
                             const float* __restrict__ l1w, const float* __restrict__ l1b,
                             const float* __restrict__ l2w, const float* __restrict__ l2b,
                             float* __restrict__ out) {
    int idx = blockIdx.x * 256 + threadIdx.x;
    if (idx >= B_N * T_LEN) return;
    int t = idx % T_LEN; int b = idx / T_LEN;
    const float scale = 0.18257418583505536f; // sqrt(1/30)
    float rbuf[64];
    const float* srow = skip + (size_t)b * 64 * T_LEN + t;
    #pragma unroll
    for (int s = 0; s < 64; ++s) {
        float v = srow[(size_t)s * T_LEN] * scale;
        rbuf[s] = v > 0.f ? v : 0.f;
    }
    float oacc = l2b[0];
    for (int cch = 0; cch < 64; ++cch) {
        float a = l1b[cch];
        const float* wrow = l1w + (size_t)cch * 64;
        #pragma unroll
        for (int s = 0; s < 64; ++s) a = fmaf(wrow[s], rbuf[s], a);
        a = a > 0.f ? a : 0.f;
        oacc = fmaf(l2w[cch], a, oacc);
    }
    out[idx] = oacc;
}

// ---------------- launch ----------------
extern "C" void kernel_launch(void* const* d_in, const int* in_sizes, int n_in,
                              void* d_out, int out_size, void* d_ws, size_t ws_size,
                              hipStream_t stream) {
    const float* c          = (const float*)d_in[0];
    const float* noise      = (const float*)d_in[1];
    const float* first_w    = (const float*)d_in[2];
    const float* first_b    = (const float*)d_in[3];
    const float* up_in_w    = (const float*)d_in[4];
    const float* up_conv_w  = (const float*)d_in[5];
    const float* blk_conv_w = (const float*)d_in[6];
    const float* blk_conv_b = (const float*)d_in[7];
    const float* blk_aux_w  = (const float*)d_in[8];
    const float* blk_out_w  = (const float*)d_in[9];
    const float* blk_out_b  = (const float*)d_in[10];
    const float* blk_skip_w = (const float*)d_in[11];
    const float* blk_skip_b = (const float*)d_in[12];
    const float* last1_w    = (const float*)d_in[13];
    const float* last1_b    = (const float*)d_in[14];
    const float* last2_w    = (const float*)d_in[15];
    const float* last2_b    = (const float*)d_in[16];
    float* out = (float*)d_out;
    float* ws  = (float*)d_ws;

    size_t off = 0;
    float* cu0  = ws + off; off += 96256;
    float* g    = ws + off; off += 30ull * 4 * 128 * T_MEL;   // 4,608,000
    float* filt = ws + off; off += 128;
    float* skip = ws + off; off += 4ull * 64 * T_LEN;         // 19,660,800
    unsigned short* base16 = (unsigned short*)(ws + off);
    size_t o16 = 0;
    const size_t XPLANE = (size_t)B_N * T_LEN * 64;           // 19,660,800 ushorts
    unsigned short* xAh = base16 + o16; o16 += XPLANE;
    unsigned short* xAl = base16 + o16; o16 += XPLANE;
    unsigned short* xBh = base16 + o16; o16 += XPLANE;
    unsigned short* xBl = base16 + o16; o16 += XPLANE;
    unsigned short* wfh = base16 + o16; o16 += 30ull * 24576;
    unsigned short* wfl = base16 + o16; o16 += 30ull * 24576;
    unsigned short* w2h = base16 + o16; o16 += 30ull * 8192;
    unsigned short* w2l = base16 + o16; o16 += 30ull * 8192;
    if (ws_size < off * sizeof(float) + o16 * sizeof(unsigned short)) return;

    hipLaunchKernelGGL(cu0_kernel, dim3((B_N * 80 * T_MEL + 255) / 256), dim3(256), 0, stream,
                       c, up_in_w, cu0);
    hipLaunchKernelGGL(filt_kernel, dim3(1), dim3(64), 0, stream, up_conv_w, filt);
    hipLaunchKernelGGL(g_kernel, dim3((30 * B_N * 128 * T_MEL + 255) / 256), dim3(256), 0, stream,
                       cu0, blk_aux_w, g);
    hipLaunchKernelGGL(first_kernel, dim3((B_N * T_LEN * 64 + 255) / 256), dim3(256), 0, stream,
                       noise, first_w, first_b, xAh, xAl);
    hipLaunchKernelGGL(wfrag_kernel, dim3((30 * 3 * 2 * 8 * 64 + 255) / 256), dim3(256), 0, stream,
                       blk_conv_w, wfh, wfl);
    hipLaunchKernelGGL(w2frag_kernel, dim3((30 * 2 * 8 * 64 + 255) / 256), dim3(256), 0, stream,
                       blk_skip_w, blk_out_w, w2h, w2l);

    for (int i = 0; i < 30; ++i) {
        int dd = 1 << (i % 10);
        const unsigned short* xih = (i & 1) ? xBh : xAh;
        const unsigned short* xil = (i & 1) ? xBl : xAl;
        unsigned short* xoh       = (i & 1) ? xAh : xBh;
        unsigned short* xol       = (i & 1) ? xAl : xBl;
        hipLaunchKernelGGL(block_kernel, dim3(T_LEN / 128, B_N), dim3(256), 0, stream,
                           xih, xil, xoh, xol, skip,
                           g + (size_t)i * 4 * 128 * T_MEL, filt,
                           wfh + (size_t)i * 24576, wfl + (size_t)i * 24576,
                           blk_conv_b + (size_t)i * 128,
                           w2h + (size_t)i * 8192, w2l + (size_t)i * 8192,
                           blk_skip_b + (size_t)i * 64,
                           blk_out_b + (size_t)i * 64,
                           dd, i == 0 ? 1 : 0);
    }

    hipLaunchKernelGGL(final_kernel, dim3((B_N * T_LEN + 255) / 256), dim3(256), 0, stream,
                       skip, last1_w, last1_b, last2_w, last2_b, out);
}

// Round 5
// 4272.978 us; speedup vs baseline: 2.2136x; 2.1296x over previous
//
#include <hip/hip_runtime.h>
#include <math.h>

#define T_LEN 76800
#define T_MEL 300
#define B_N 4

typedef __attribute__((ext_vector_type(8))) short bf16x8;
typedef __attribute__((ext_vector_type(4))) float f32x4;
typedef __attribute__((ext_vector_type(4))) unsigned short u16x4;

__device__ inline unsigned short f2bf(float x) {
    unsigned u = __float_as_uint(x);
    u += 0x7fffu + ((u >> 16) & 1u);
    return (unsigned short)(u >> 16);
}
__device__ inline float bf2f(unsigned short h) {
    return __uint_as_float(((unsigned)h) << 16);
}

// ---------------- prep kernels ----------------

__global__ void cu0_kernel(const float* __restrict__ c, const float* __restrict__ up_in_w,
                           float* __restrict__ cu0) {
    int idx = blockIdx.x * 256 + threadIdx.x;
    if (idx >= B_N * 80 * T_MEL) return;
    int m = idx % T_MEL; int rest = idx / T_MEL; int o = rest % 80; int b = rest / 80;
    const float* crow = c + (size_t)(b * 80) * T_MEL;
    const float* wrow = up_in_w + o * 80;
    float acc = 0.f;
    for (int i = 0; i < 80; ++i) acc = fmaf(wrow[i], crow[(size_t)i * T_MEL + m], acc);
    cu0[idx] = acc;
}

// composite 33-tap filter prefix sums + exact edge vectors (r1 derivation, validated)
__global__ void filt_kernel(const float* __restrict__ up_conv_w, float* __restrict__ filt) {
    if (threadIdx.x != 0 || blockIdx.x != 0) return;
    float F[33], tmp[33];
    for (int j = 0; j < 9; ++j) F[j] = up_conv_w[j];
    int len = 9;
    for (int s = 1; s < 4; ++s) {
        const float* w = up_conv_w + s * 9;
        int nl = len + 8;
        for (int j = 0; j < nl; ++j) {
            float acc = 0.f;
            for (int a = 0; a < 9; ++a) { int bi = j - a; if (bi >= 0 && bi < len) acc += w[a] * F[bi]; }
            tmp[j] = acc;
        }
        for (int j = 0; j < nl; ++j) F[j] = tmp[j];
        len = nl;
    }
    float run = 0.f;
    for (int n = 0; n < 33; ++n) { filt[n] = run; run += F[n]; }
    filt[33] = run; filt[34] = run;
    const float* w1 = up_conv_w + 0;  const float* w2 = up_conv_w + 9;
    const float* w3 = up_conv_w + 18; const float* w4 = up_conv_w + 27;
    {
        float y1[28], y2[24], y3[20];
        for (int u = 0; u < 28; ++u) { float a = 0; for (int k = 0; k < 9; ++k) { int v = u + k - 4; if (v >= 0) a += w1[k]; } y1[u] = a; }
        for (int u = 0; u < 24; ++u) { float a = 0; for (int k = 0; k < 9; ++k) { int v = u + k - 4; if (v >= 0) a += w2[k] * y1[v]; } y2[u] = a; }
        for (int u = 0; u < 20; ++u) { float a = 0; for (int k = 0; k < 9; ++k) { int v = u + k - 4; if (v >= 0) a += w3[k] * y2[v]; } y3[u] = a; }
        for (int t = 0; t < 16; ++t) { float a = 0; for (int k = 0; k < 9; ++k) { int v = t + k - 4; if (v >= 0) a += w4[k] * y3[v]; } filt[40 + t] = a; }
    }
    {
        float z1[44], z2[44], z3[44];
        for (int u = 0; u < 44; ++u) { float a = 0; for (int k = 0; k < 9; ++k) { int v = u + k - 4; if (v <= 43) a += w1[k]; } z1[u] = a; }
        for (int u = 0; u < 44; ++u) { float a = 0; for (int k = 0; k < 9; ++k) { int v = u + k - 4; if (v <= 43) a += w2[k] * z1[v < 0 ? 0 : v]; } z2[u] = a; }
        for (int u = 0; u < 44; ++u) { float a = 0; for (int k = 0; k < 9; ++k) { int v = u + k - 4; if (v <= 43) a += w3[k] * z2[v < 0 ? 0 : v]; } z3[u] = a; }
        for (int j = 0; j < 16; ++j) {
            int u = 28 + j; float a = 0;
            for (int k = 0; k < 9; ++k) { int v = u + k - 4; if (v <= 43) a += w4[k] * z3[v < 0 ? 0 : v]; }
            filt[56 + j] = a;
        }
    }
}

__global__ void g_kernel(const float* __restrict__ cu0, const float* __restrict__ aux_w,
                         float* __restrict__ g) {
    int idx = blockIdx.x * 256 + threadIdx.x;
    if (idx >= 30 * B_N * 128 * T_MEL) return;
    int m = idx % T_MEL; int rest = idx / T_MEL; int o = rest % 128; rest /= 128;
    int b = rest % B_N; int i = rest / B_N;
    const float* wrow = aux_w + ((size_t)i * 128 + o) * 80;
    const float* crow = cu0 + (size_t)(b * 80) * T_MEL + m;
    float acc = 0.f;
    for (int cc = 0; cc < 80; ++cc) acc = fmaf(wrow[cc], crow[(size_t)cc * T_MEL], acc);
    g[idx] = acc;
}

// x0 in [b][t][ch] split-bf16 layout
__global__ void first_kernel(const float* __restrict__ noise, const float* __restrict__ fw,
                             const float* __restrict__ fb,
                             unsigned short* __restrict__ xh, unsigned short* __restrict__ xl) {
    int idx = blockIdx.x * 256 + threadIdx.x;
    if (idx >= B_N * T_LEN * 64) return;
    int i = idx & 63; int rest = idx >> 6; int t = rest % T_LEN; int b = rest / T_LEN;
    float v = fmaf(fw[i], noise[(size_t)b * T_LEN + t], fb[i]);
    unsigned short h = f2bf(v);
    xh[idx] = h;
    xl[idx] = f2bf(v - bf2f(h));
}

// conv weights -> MFMA A-fragment order, hi/lo planes.
// idx = (((layer*3+tap)*2+ch)*8+m)*64+lane ; elem j: o=m*16+(l&15), i=ch*32+(l>>4)*8+j
__global__ void wfrag_kernel(const float* __restrict__ conv_w,
                             unsigned short* __restrict__ wfh, unsigned short* __restrict__ wfl) {
    int idx = blockIdx.x * 256 + threadIdx.x;
    if (idx >= 30 * 3 * 2 * 8 * 64) return;
    int l = idx & 63; int r = idx >> 6;
    int m = r & 7; r >>= 3;
    int ch = r & 1; r >>= 1;
    int tap = r % 3; int layer = r / 3;
    int o = m * 16 + (l & 15);
    int i0 = ch * 32 + (l >> 4) * 8;
    #pragma unroll
    for (int j = 0; j < 8; ++j) {
        float v = conv_w[(((size_t)layer * 128 + o) * 64 + i0 + j) * 3 + tap];
        unsigned short h = f2bf(v);
        wfh[(size_t)idx * 8 + j] = h;
        wfl[(size_t)idx * 8 + j] = f2bf(v - bf2f(h));
    }
}

// skip/out weights -> fragment order. idx = ((layer*2+ch)*8+m)*64+lane
__global__ void w2frag_kernel(const float* __restrict__ skip_w, const float* __restrict__ out_w,
                              unsigned short* __restrict__ w2h, unsigned short* __restrict__ w2l) {
    int idx = blockIdx.x * 256 + threadIdx.x;
    if (idx >= 30 * 2 * 8 * 64) return;
    int l = idx & 63; int r = idx >> 6;
    int m = r & 7; r >>= 3;
    int ch = r & 1; int layer = r >> 1;
    int o = m * 16 + (l & 15);
    int z0 = ch * 32 + (l >> 4) * 8;
    #pragma unroll
    for (int j = 0; j < 8; ++j) {
        float v = (o < 64) ? skip_w[((size_t)layer * 64 + o) * 64 + z0 + j]
                           : out_w[((size_t)layer * 64 + (o - 64)) * 64 + z0 + j];
        unsigned short h = f2bf(v);
        w2h[(size_t)idx * 8 + j] = h;
        w2l[(size_t)idx * 8 + j] = f2bf(v - bf2f(h));
    }
}

// ---------------- main residual block ----------------
// 256 thr = 4 waves; tile 128 o-rows x 128 t (wave wv: t in [wv*32, wv*32+32)).
// Phase1: 6 stages (tap,ch); W frags LDS-staged (double-buffered, shared by 4 waves);
//         x B-frags direct global loads from [b][t][ch] split planes.
// Gate in-register -> phase2 in two 32-zc rounds (Z through small LDS region that
// reuses the W-stage buffer). launch_bounds(256,3): total regs <=168 -> 12 waves/CU.
__global__ __launch_bounds__(256, 3) void block_kernel(
    const unsigned short* __restrict__ xin_h, const unsigned short* __restrict__ xin_l,
    unsigned short* __restrict__ xout_h, unsigned short* __restrict__ xout_l,
    float* __restrict__ skip,   // [b][t][64]
    const float* __restrict__ g, const float* __restrict__ filt,
    const unsigned short* __restrict__ wfh, const unsigned short* __restrict__ wfl,
    const float* __restrict__ conv_b,
    const unsigned short* __restrict__ w2h, const unsigned short* __restrict__ w2l,
    const float* __restrict__ skip_b, const float* __restrict__ out_b,
    int d, int first)
{
    // union region: phase1 = W stages [2 bufs][hi 4096 | lo 4096]; phase2 = Z (10240 ush)
    __shared__ unsigned short U[16384];
    __shared__ float glm[128], gll[128], glr[128], bl1[128], bl2[128];

    const int tid = threadIdx.x;
    const int wv = tid >> 6, ln = tid & 63;
    const int g4 = ln >> 4, l15 = ln & 15;
    const int b = blockIdx.y;
    // XCD-chunked swizzle: 600 WGs, 75 per XCD chunk (bijective)
    const int bx = (blockIdx.x & 7) * 75 + (blockIdx.x >> 3);
    const int t0 = bx * 128;
    const int m0 = t0 >> 8;

    if (tid < 128) {
        int o = tid;
        const float* gb = g + ((size_t)b * 128 + o) * T_MEL;
        int ml = m0 > 0 ? m0 - 1 : 0;
        int mr = m0 < 299 ? m0 + 1 : 299;
        glm[o] = gb[m0]; gll[o] = gb[ml]; glr[o] = gb[mr];
        bl1[o] = conv_b[o];
    } else {
        int o = tid - 128;
        bl2[o] = (o < 64) ? skip_b[o] : out_b[o - 64];
    }

    // prologue: stage W s=0 into buf 0
    {
        const size_t gb_ = (size_t)0 * 4096 + tid * 16;
        bf16x8 h0 = *(const bf16x8*)(wfh + gb_);
        bf16x8 h1 = *(const bf16x8*)(wfh + gb_ + 8);
        bf16x8 l0 = *(const bf16x8*)(wfl + gb_);
        bf16x8 l1 = *(const bf16x8*)(wfl + gb_ + 8);
        *(bf16x8*)&U[tid * 16] = h0;      *(bf16x8*)&U[tid * 16 + 8] = h1;
        *(bf16x8*)&U[4096 + tid * 16] = l0; *(bf16x8*)&U[4096 + tid * 16 + 8] = l1;
    }
    __syncthreads();

    // per-ntile aux interpolation coefficients (exact)
    float am[2], al[2], ar[2];
    const float K = filt[34];
    #pragma unroll
    for (int nt = 0; nt < 2; ++nt) {
        int t = t0 + wv * 32 + nt * 16 + l15;
        int r = t & 255;
        float Am = K, Al = 0.f, Ar = 0.f;
        if (t < 16)               { Am = filt[40 + t]; }
        else if (t >= T_LEN - 16) { Am = filt[56 + (t - (T_LEN - 16))]; }
        else if (r < 16)  { float blv = filt[16 - r];     Am = K - blv; Al = blv; }
        else if (r > 239) { float bh = K - filt[272 - r]; Am = K - bh;  Ar = bh; }
        am[nt] = Am; al[nt] = Al; ar[nt] = Ar;
    }

    f32x4 acc[8][2];
    #pragma unroll
    for (int m = 0; m < 8; ++m)
        #pragma unroll
        for (int nt = 0; nt < 2; ++nt)
            #pragma unroll
            for (int r = 0; r < 4; ++r) {
                int o = m * 16 + 4 * g4 + r;
                acc[m][nt][r] = bl1[o] + am[nt] * glm[o] + al[nt] * gll[o] + ar[nt] * glr[o];
            }

    bf16x8 zfrag;
    #pragma unroll
    for (int j = 0; j < 8; ++j) zfrag[j] = 0;

    const size_t xbase = (size_t)b * T_LEN * 64;

    // ---- phase 1: 6 stages (tap,ch), W from LDS (dbuf), x from global ----
    #pragma unroll
    for (int s = 0; s < 6; ++s) {
        const int cur = s & 1;
        if (s < 5) {  // stage next into the other buffer
            const size_t gb_ = (size_t)(s + 1) * 4096 + tid * 16;
            bf16x8 h0 = *(const bf16x8*)(wfh + gb_);
            bf16x8 h1 = *(const bf16x8*)(wfh + gb_ + 8);
            bf16x8 l0 = *(const bf16x8*)(wfl + gb_);
            bf16x8 l1 = *(const bf16x8*)(wfl + gb_ + 8);
            unsigned short* dst = U + (cur ^ 1) * 8192;
            *(bf16x8*)&dst[tid * 16] = h0;        *(bf16x8*)&dst[tid * 16 + 8] = h1;
            *(bf16x8*)&dst[4096 + tid * 16] = l0; *(bf16x8*)&dst[4096 + tid * 16 + 8] = l1;
        }
        const int tap = s >> 1, ch = s & 1;
        const int shift = (tap - 1) * d;
        bf16x8 bxh[2], bxl[2];
        #pragma unroll
        for (int nt = 0; nt < 2; ++nt) {
            int te = t0 + wv * 32 + nt * 16 + l15 + shift;
            if ((unsigned)te < (unsigned)T_LEN) {
                size_t a = xbase + (size_t)te * 64 + ch * 32 + g4 * 8;
                bxh[nt] = *(const bf16x8*)(xin_h + a);
                bxl[nt] = *(const bf16x8*)(xin_l + a);
            } else {
                bxh[nt] = zfrag; bxl[nt] = zfrag;
            }
        }
        const unsigned short* Wh = U + cur * 8192;
        const unsigned short* Wl = Wh + 4096;
        #pragma unroll
        for (int m = 0; m < 8; ++m) {
            const bf16x8 ah  = *(const bf16x8*)&Wh[(m * 64 + ln) * 8];
            const bf16x8 alo = *(const bf16x8*)&Wl[(m * 64 + ln) * 8];
            #pragma unroll
            for (int nt = 0; nt < 2; ++nt) {
                acc[m][nt] = __builtin_amdgcn_mfma_f32_16x16x32_bf16(ah,  bxh[nt], acc[m][nt], 0, 0, 0);
                acc[m][nt] = __builtin_amdgcn_mfma_f32_16x16x32_bf16(ah,  bxl[nt], acc[m][nt], 0, 0, 0);
                acc[m][nt] = __builtin_amdgcn_mfma_f32_16x16x32_bf16(alo, bxh[nt], acc[m][nt], 0, 0, 0);
            }
        }
        __syncthreads();
    }

    // ---- phase 2: two zc-rounds through small Z region (reuses U) ----
    unsigned short* Zh = U;          // [128 t][40] (pad 40 for bank spread)
    unsigned short* Zl = U + 5120;

    f32x4 acc2[8][2];
    #pragma unroll
    for (int m = 0; m < 8; ++m)
        #pragma unroll
        for (int nt = 0; nt < 2; ++nt)
            #pragma unroll
            for (int r = 0; r < 4; ++r)
                acc2[m][nt][r] = bl2[m * 16 + 4 * g4 + r];

    #pragma unroll
    for (int rd = 0; rd < 2; ++rd) {
        // gate + write z for zm = 2rd, 2rd+1 (acc halves die here -> frees regs)
        #pragma unroll
        for (int zi = 0; zi < 2; ++zi) {
            int zm = 2 * rd + zi;
            #pragma unroll
            for (int nt = 0; nt < 2; ++nt) {
                u16x4 zh4, zl4;
                #pragma unroll
                for (int r = 0; r < 4; ++r) {
                    float a_ = acc[zm][nt][r], b_ = acc[zm + 4][nt][r];
                    float z = tanhf(a_) * (1.f / (1.f + expf(-b_)));
                    unsigned short h = f2bf(z);
                    zh4[r] = h; zl4[r] = f2bf(z - bf2f(h));
                }
                int trow = wv * 32 + nt * 16 + l15;
                int col = zi * 16 + 4 * g4;
                *(u16x4*)&Zh[trow * 40 + col] = zh4;
                *(u16x4*)&Zl[trow * 40 + col] = zl4;
            }
        }
        __syncthreads();
        bf16x8 bzh[2], bzl[2];
        #pragma unroll
        for (int nt = 0; nt < 2; ++nt) {
            int trow = wv * 32 + nt * 16 + l15;
            bzh[nt] = *(const bf16x8*)&Zh[trow * 40 + g4 * 8];
            bzl[nt] = *(const bf16x8*)&Zl[trow * 40 + g4 * 8];
        }
        #pragma unroll
        for (int m = 0; m < 8; ++m) {
            const bf16x8 ah  = *(const bf16x8*)(w2h + ((size_t)((rd * 8 + m) * 64 + ln)) * 8);
            const bf16x8 alo = *(const bf16x8*)(w2l + ((size_t)((rd * 8 + m) * 64 + ln)) * 8);
            #pragma unroll
            for (int nt = 0; nt < 2; ++nt) {
                acc2[m][nt] = __builtin_amdgcn_mfma_f32_16x16x32_bf16(ah,  bzh[nt], acc2[m][nt], 0, 0, 0);
                acc2[m][nt] = __builtin_amdgcn_mfma_f32_16x16x32_bf16(ah,  bzl[nt], acc2[m][nt], 0, 0, 0);
                acc2[m][nt] = __builtin_amdgcn_mfma_f32_16x16x32_bf16(alo, bzh[nt], acc2[m][nt], 0, 0, 0);
            }
        }
        if (rd == 0) __syncthreads();
    }

    // ---- epilogue: skip [b][t][64] accumulate; x residual [b][t][ch] ----
    const size_t sbase = (size_t)b * T_LEN * 64;
    #pragma unroll
    for (int m = 0; m < 4; ++m)
        #pragma unroll
        for (int nt = 0; nt < 2; ++nt) {
            int t = t0 + wv * 32 + nt * 16 + l15;
            int o0 = m * 16 + 4 * g4;
            float* sp = skip + sbase + (size_t)t * 64 + o0;
            float4 v = make_float4(acc2[m][nt][0], acc2[m][nt][1], acc2[m][nt][2], acc2[m][nt][3]);
            if (!first) {
                float4 o = *(const float4*)sp;
                v.x += o.x; v.y += o.y; v.z += o.z; v.w += o.w;
            }
            *(float4*)sp = v;
        }
    #pragma unroll
    for (int m = 4; m < 8; ++m)
        #pragma unroll
        for (int nt = 0; nt < 2; ++nt) {
            int t = t0 + wv * 32 + nt * 16 + l15;
            int o0 = (m - 4) * 16 + 4 * g4;
            size_t a = xbase + (size_t)t * 64 + o0;
            u16x4 xh4 = *(const u16x4*)(xin_h + a);
            u16x4 xl4 = *(const u16x4*)(xin_l + a);
            u16x4 oh, ol;
            #pragma unroll
            for (int r = 0; r < 4; ++r) {
                float xi = bf2f(xh4[r]) + bf2f(xl4[r]);
                float v = (acc2[m][nt][r] + xi) * 0.25f;
                unsigned short h = f2bf(v);
                oh[r] = h; ol[r] = f2bf(v - bf2f(h));
            }
            *(u16x4*)(xout_h + a) = oh;
            *(u16x4*)(xout_l + a) = ol;
        }
}

// ---------------- epilogue ----------------
__global__ void final_kernel(const float* __restrict__ skip,
                             const float* __restrict__ l1w, const float* __restrict__ l1b,
                             const float* __restrict__ l2w, const float* __restrict__ l2b,
                             float* __restrict__ out) {
    int idx = blockIdx.x * 256 + threadIdx.x;
    if (idx >= B_N * T_LEN) return;
    int t = idx % T_LEN; int b = idx / T_LEN;
    const float scale = 0.18257418583505536f; // sqrt(1/30)
    float rbuf[64];
    const float* srow = skip + ((size_t)b * T_LEN + t) * 64;
    #pragma unroll
    for (int s = 0; s < 64; ++s) {
        float v = srow[s] * scale;
        rbuf[s] = v > 0.f ? v : 0.f;
    }
    float oacc = l2b[0];
    for (int cch = 0; cch < 64; ++cch) {
        float a = l1b[cch];
        const float* wrow = l1w + (size_t)cch * 64;
        #pragma unroll
        for (int s = 0; s < 64; ++s) a = fmaf(wrow[s], rbuf[s], a);
        a = a > 0.f ? a : 0.f;
        oacc = fmaf(l2w[cch], a, oacc);
    }
    out[idx] = oacc;
}

// ---------------- launch ----------------
extern "C" void kernel_launch(void* const* d_in, const int* in_sizes, int n_in,
                              void* d_out, int out_size, void* d_ws, size_t ws_size,
                              hipStream_t stream) {
    const float* c          = (const float*)d_in[0];
    const float* noise      = (const float*)d_in[1];
    const float* first_w    = (const float*)d_in[2];
    const float* first_b    = (const float*)d_in[3];
    const float* up_in_w    = (const float*)d_in[4];
    const float* up_conv_w  = (const float*)d_in[5];
    const float* blk_conv_w = (const float*)d_in[6];
    const float* blk_conv_b = (const float*)d_in[7];
    const float* blk_aux_w  = (const float*)d_in[8];
    const float* blk_out_w  = (const float*)d_in[9];
    const float* blk_out_b  = (const float*)d_in[10];
    const float* blk_skip_w = (const float*)d_in[11];
    const float* blk_skip_b = (const float*)d_in[12];
    const float* last1_w    = (const float*)d_in[13];
    const float* last1_b    = (const float*)d_in[14];
    const float* last2_w    = (const float*)d_in[15];
    const float* last2_b    = (const float*)d_in[16];
    float* out = (float*)d_out;
    float* ws  = (float*)d_ws;

    size_t off = 0;
    float* cu0  = ws + off; off += 96256;
    float* g    = ws + off; off += 30ull * 4 * 128 * T_MEL;   // 4,608,000
    float* filt = ws + off; off += 128;
    float* skip = ws + off; off += 4ull * 64 * T_LEN;         // [b][t][64]
    unsigned short* base16 = (unsigned short*)(ws + off);
    size_t o16 = 0;
    const size_t XPLANE = (size_t)B_N * T_LEN * 64;
    unsigned short* xAh = base16 + o16; o16 += XPLANE;
    unsigned short* xAl = base16 + o16; o16 += XPLANE;
    unsigned short* xBh = base16 + o16; o16 += XPLANE;
    unsigned short* xBl = base16 + o16; o16 += XPLANE;
    unsigned short* wfh = base16 + o16; o16 += 30ull * 24576;
    unsigned short* wfl = base16 + o16; o16 += 30ull * 24576;
    unsigned short* w2h = base16 + o16; o16 += 30ull * 8192;
    unsigned short* w2l = base16 + o16; o16 += 30ull * 8192;
    if (ws_size < off * sizeof(float) + o16 * sizeof(unsigned short)) return;

    hipLaunchKernelGGL(cu0_kernel, dim3((B_N * 80 * T_MEL + 255) / 256), dim3(256), 0, stream,
                       c, up_in_w, cu0);
    hipLaunchKernelGGL(filt_kernel, dim3(1), dim3(64), 0, stream, up_conv_w, filt);
    hipLaunchKernelGGL(g_kernel, dim3((30 * B_N * 128 * T_MEL + 255) / 256), dim3(256), 0, stream,
                       cu0, blk_aux_w, g);
    hipLaunchKernelGGL(first_kernel, dim3((B_N * T_LEN * 64 + 255) / 256), dim3(256), 0, stream,
                       noise, first_w, first_b, xAh, xAl);
    hipLaunchKernelGGL(wfrag_kernel, dim3((30 * 3 * 2 * 8 * 64 + 255) / 256), dim3(256), 0, stream,
                       blk_conv_w, wfh, wfl);
    hipLaunchKernelGGL(w2frag_kernel, dim3((30 * 2 * 8 * 64 + 255) / 256), dim3(256), 0, stream,
                       blk_skip_w, blk_out_w, w2h, w2l);

    for (int i = 0; i < 30; ++i) {
        int dd = 1 << (i % 10);
        const unsigned short* xih = (i & 1) ? xBh : xAh;
        const unsigned short* xil = (i & 1) ? xBl : xAl;
        unsigned short* xoh       = (i & 1) ? xAh : xBh;
        unsigned short* xol       = (i & 1) ? xAl : xBl;
        hipLaunchKernelGGL(block_kernel, dim3(T_LEN / 128, B_N), dim3(256), 0, stream,
                           xih, xil, xoh, xol, skip,
                           g + (size_t)i * 4 * 128 * T_MEL, filt,
                           wfh + (size_t)i * 24576, wfl + (size_t)i * 24576,
                           blk_conv_b + (size_t)i * 128,
                           w2h + (size_t)i * 8192, w2l + (size_t)i * 8192,
                           blk_skip_b + (size_t)i * 64,
                           blk_out_b + (size_t)i * 64,
                           dd, i == 0 ? 1 : 0);
    }

    hipLaunchKernelGGL(final_kernel, dim3((B_N * T_LEN + 255) / 256), dim3(256), 0, stream,
                       skip, last1_w, last1_b, last2_w, last2_b, out);
}